// Round 6
// baseline (246.726 us; speedup 1.0000x reference)
//
#include <hip/hip_runtime.h>

typedef short bfrag __attribute__((ext_vector_type(8)));   // 8 bf16 (4 VGPRs)
typedef float f32x4 __attribute__((ext_vector_type(4)));   // MFMA accumulator

#define MFMA16(a, b, c) __builtin_amdgcn_mfma_f32_16x16x32_bf16((a), (b), (c), 0, 0, 0)

// b=2, s=2048, d=1024, h=16, hd=64, R=257, w=128, scale=sqrt(64)=8
#define SEQ   2048
#define DMOD  1024
#define NHEAD 16
#define HDIM  64
#define RSZ   257
#define RPADN 272     // 17*16, zero-padded
#define XN    (4096*1024)
#define WN    (3072*1024)
#define LOG2E 1.44269504f

__device__ __forceinline__ unsigned short f2bf(float f) {
  unsigned int u = __float_as_uint(f);
  u += 0x7FFFu + ((u >> 16) & 1u);   // round-to-nearest-even
  return (unsigned short)(u >> 16);
}
__device__ __forceinline__ float bf2f(unsigned short u) {
  return __uint_as_float(((unsigned int)u) << 16);
}
// packed f32x2 -> bf16x2 (single v_cvt_pk_bf16_f32 on gfx950)
__device__ __forceinline__ unsigned int pkbf(float a, float b) {
#if defined(__gfx950__)
  unsigned int r;
  asm("v_cvt_pk_bf16_f32 %0, %1, %2" : "=v"(r) : "v"(a), "v"(b));
  return r;
#else
  return (unsigned int)f2bf(a) | ((unsigned int)f2bf(b) << 16);
#endif
}
__device__ __forceinline__ float fexp2(float x) {
#if __has_builtin(__builtin_amdgcn_exp2f)
  return __builtin_amdgcn_exp2f(x);
#else
  return __expf(x * 0.69314718f);
#endif
}
__device__ __forceinline__ void gl2lds16(const void* g, void* l) {
  __builtin_amdgcn_global_load_lds(
      (__attribute__((address_space(1))) void*)(g),
      (__attribute__((address_space(3))) void*)(l), 16, 0, 0);
}

// ------------------- fused cast kernel -------------------
__global__ __launch_bounds__(256) void cast_all(const float* __restrict__ x,
                                                const float* __restrict__ Wqkv,
                                                const float* __restrict__ Wr,
                                                unsigned short* __restrict__ xb,
                                                unsigned short* __restrict__ wb,
                                                unsigned short* __restrict__ wrb) {
  int i = (blockIdx.x * 256 + threadIdx.x) * 4;
  if (i < XN) {
    float4 v = *(const float4*)(x + i);
    ushort4 o; o.x = f2bf(v.x); o.y = f2bf(v.y); o.z = f2bf(v.z); o.w = f2bf(v.w);
    *(ushort4*)(xb + i) = o;
  } else if (i < XN + WN) {
    int j = i - XN;
    float4 v = *(const float4*)(Wqkv + j);
    ushort4 o; o.x = f2bf(v.x); o.y = f2bf(v.y); o.z = f2bf(v.z); o.w = f2bf(v.w);
    *(ushort4*)(wb + j) = o;
  } else {
    int j = i - XN - WN;      // 0 .. 17407, 4 at a time
    ushort4 o;
    unsigned short t[4];
#pragma unroll
    for (int k = 0; k < 4; ++k)
      t[k] = (j + k < RSZ * HDIM) ? f2bf(Wr[j + k]) : (unsigned short)0;
    o.x = t[0]; o.y = t[1]; o.z = t[2]; o.w = t[3];
    *(ushort4*)(wrb + j) = o;
  }
}

// ------------------- QKV projection GEMM -------------------
// 128x128 tile, BK=64. Epilogue: LDS repack (reusing As/Bs) -> coalesced
// 16B stores into qb/kbuf/vb (all [bh][s][64]); V transposed by vtrans.
__global__ __launch_bounds__(256) void qkv_gemm(const unsigned short* __restrict__ xb,
                                                const unsigned short* __restrict__ wb,
                                                const float* __restrict__ bqkv,
                                                unsigned short* __restrict__ qb,
                                                unsigned short* __restrict__ kbuf,
                                                unsigned short* __restrict__ vb) {
  __shared__ unsigned short SMEM[2 * 128 * 64];   // As | Bs, reused as C 128x128
  unsigned short* As = SMEM;
  unsigned short* Bs = SMEM + 128 * 64;
  const int tid = threadIdx.x;
  const int m0 = blockIdx.y * 128, n0 = blockIdx.x * 128;
  const int wave = tid >> 6, lane = tid & 63;
  const int q4 = lane >> 4, l16 = lane & 15;
  const int wm = (wave & 1) * 64, wn = (wave >> 1) * 64;
  const int sw = l16 & 7;

  f32x4 acc[4][4];
#pragma unroll
  for (int rt = 0; rt < 4; ++rt)
#pragma unroll
    for (int ct = 0; ct < 4; ++ct) acc[rt][ct] = (f32x4){0.f, 0.f, 0.f, 0.f};

  for (int k0 = 0; k0 < DMOD; k0 += 64) {
#pragma unroll
    for (int it = 0; it < 4; ++it) {
      int ch = it * 256 + tid;
      int r = ch >> 3, cl = (ch & 7) ^ (r & 7);
      gl2lds16(xb + (size_t)(m0 + r) * DMOD + k0 + cl * 8, As + ch * 8);
      gl2lds16(wb + (size_t)(n0 + r) * DMOD + k0 + cl * 8, Bs + ch * 8);
    }
    __syncthreads();
#pragma unroll
    for (int ks = 0; ks < 2; ++ks) {
      bfrag af[4], bf[4];
#pragma unroll
      for (int rt = 0; rt < 4; ++rt)
        af[rt] = *(const bfrag*)(As + (wm + rt * 16 + l16) * 64 + ((ks * 4 + q4) ^ sw) * 8);
#pragma unroll
      for (int ct = 0; ct < 4; ++ct)
        bf[ct] = *(const bfrag*)(Bs + (wn + ct * 16 + l16) * 64 + ((ks * 4 + q4) ^ sw) * 8);
#pragma unroll
      for (int rt = 0; rt < 4; ++rt)
#pragma unroll
        for (int ct = 0; ct < 4; ++ct)
          acc[rt][ct] = MFMA16(af[rt], bf[ct], acc[rt][ct]);
    }
    __syncthreads();
  }

  // ---- epilogue: C -> LDS (chunk-swizzled) -> coalesced 16B stores ----
  unsigned short* Cs = SMEM;   // 128 x 128 bf16
#pragma unroll
  for (int rt = 0; rt < 4; ++rt) {
#pragma unroll
    for (int ct = 0; ct < 4; ++ct) {
      int n = wn + ct * 16 + l16;        // tile-local col 0..127
      float bias = bqkv[n0 + n];
      int c = n >> 3, nl = n & 7;
#pragma unroll
      for (int reg = 0; reg < 4; ++reg) {
        int m = wm + rt * 16 + q4 * 4 + reg;
        int s = ((m >> 3) ^ m) & 7;
        Cs[m * 128 + ((c ^ s) << 3) + nl] = f2bf(acc[rt][ct][reg] + bias);
      }
    }
  }
  __syncthreads();
#pragma unroll
  for (int it = 0; it < 8; ++it) {
    int idx = it * 256 + tid;
    int r = idx >> 4, c = idx & 15;      // row 0..127, chunk 0..15
    int s = ((r >> 3) ^ r) & 7;
    bfrag val = *(const bfrag*)(Cs + r * 128 + (((c & 8) | ((c & 7) ^ s)) << 3));
    int ng = n0 + c * 8;
    int hh = ng / 192;
    int rem = ng - hh * 192;
    int t = rem >> 6, dd = rem & 63;
    int mg = m0 + r;
    size_t o = (((size_t)((mg >> 11) * NHEAD + hh)) * SEQ + (mg & 2047)) * HDIM + dd;
    unsigned short* dst = (t == 0) ? qb : (t == 1) ? kbuf : vb;
    *(bfrag*)(dst + o) = val;
  }
}

// ------------------- V transpose: vb[bh][s][64] -> vtb[bh][64][s] ---------
__global__ __launch_bounds__(256) void vtrans(const unsigned short* __restrict__ vb,
                                              unsigned short* __restrict__ vtb) {
  __shared__ unsigned short T[64 * 80];
  const int tid = threadIdx.x;
  const int s0 = blockIdx.x * 64;
  const int bh = blockIdx.y;
  const unsigned short* src = vb + ((size_t)bh * SEQ + s0) * HDIM;
#pragma unroll
  for (int it = 0; it < 2; ++it) {
    int idx = it * 256 + tid;
    int r = idx >> 3, c = idx & 7;
    *(uint4*)(&T[r * 80 + c * 8]) = *(const uint4*)(src + r * HDIM + c * 8);
  }
  __syncthreads();
#pragma unroll
  for (int it = 0; it < 2; ++it) {
    int idx = it * 256 + tid;
    int d = idx >> 3, c = idx & 7;
    unsigned short tmp[8];
#pragma unroll
    for (int k = 0; k < 8; ++k) tmp[k] = T[(c * 8 + k) * 80 + d];
    *(uint4*)(vtb + ((size_t)bh * HDIM + d) * SEQ + s0 + c * 8) = *(uint4*)tmp;
  }
}

// ------------------- rel-pos logits (pre-scaled by log2e, bf16 out) -------
__global__ __launch_bounds__(256) void rp_gemm(const unsigned short* __restrict__ qb,
                                               const unsigned short* __restrict__ wrb,
                                               const float* __restrict__ br,
                                               unsigned short* __restrict__ rp16) {
  __shared__ unsigned short WrS[RPADN * HDIM];  // 34816 B
  __shared__ unsigned short Qs[64 * HDIM];      // 8192 B
  const int tid = threadIdx.x;
  const size_t row0 = (size_t)blockIdx.x * 64;

  for (int i = tid; i < RPADN * HDIM / 8; i += 256)
    *(uint4*)(&WrS[i * 8]) = *(const uint4*)(&wrb[i * 8]);
  for (int i = tid; i < 512; i += 256)
    *(uint4*)(&Qs[i * 8]) = *(const uint4*)(&qb[row0 * HDIM + i * 8]);
  __syncthreads();

  const int wave = tid >> 6, lane = tid & 63;
  const int q4 = lane >> 4, l16 = lane & 15;

  bfrag af0 = *(const bfrag*)(Qs + (wave * 16 + l16) * 64 + q4 * 8);
  bfrag af1 = *(const bfrag*)(Qs + (wave * 16 + l16) * 64 + 32 + q4 * 8);

#pragma unroll 4
  for (int ct = 0; ct < 17; ++ct) {
    f32x4 acc = (f32x4){0.f, 0.f, 0.f, 0.f};
    bfrag b0 = *(const bfrag*)(WrS + (ct * 16 + l16) * 64 + q4 * 8);
    bfrag b1 = *(const bfrag*)(WrS + (ct * 16 + l16) * 64 + 32 + q4 * 8);
    acc = MFMA16(af0, b0, acc);
    acc = MFMA16(af1, b1, acc);
    int col = ct * 16 + l16;
    if (col < RSZ) {
      float bias = br[col];
#pragma unroll
      for (int reg = 0; reg < 4; ++reg) {
        size_t rr = row0 + wave * 16 + q4 * 4 + reg;
        rp16[rr * RSZ + col] = f2bf((acc[reg] + bias) * LOG2E);
      }
    }
  }
}

// ------------------- flash attention, transposed-S, BN=128/barrier -------
// grid (32 qtiles, 32 bh); 256 thr. Stage K[128x64]+V[64x128] per barrier
// (40960 B LDS = exactly 4 blocks/CU), then two 64-j halves back-to-back
// (Ps is wave-private -> no barrier between halves). Barriers: 16 total.
__global__ __launch_bounds__(256) void flash_attn(const unsigned short* __restrict__ qb,
                                                  const unsigned short* __restrict__ kbuf,
                                                  const unsigned short* __restrict__ vtb,
                                                  const unsigned short* __restrict__ rp16,
                                                  float* __restrict__ out) {
  __shared__ unsigned short Ks[128 * 64];   // [j][d]
  __shared__ unsigned short Vs[64 * 128];   // [d][j]
  __shared__ unsigned short Ps[64 * 64];    // P[i][j-half]

  const int tid = threadIdx.x;
  const int i0 = blockIdx.x * 64;
  const int bh = blockIdx.y;
  const int wave = tid >> 6, lane = tid & 63;
  const int q4 = lane >> 4, l16 = lane & 15;
  const int sw = l16 & 7;
  const float SC = 0.125f * LOG2E;

  const int rloc = wave * 16 + l16;
  const int ig = i0 + rloc;                 // this lane's global Q row
  const unsigned short* qrow = qb + ((size_t)bh * SEQ + ig) * HDIM;
  bfrag qf0 = *(const bfrag*)(qrow + q4 * 8);
  bfrag qf1 = *(const bfrag*)(qrow + 32 + q4 * 8);

  const unsigned short* rpbase = rp16 + ((size_t)bh * SEQ + ig) * RSZ;
  const float rpL = bf2f(rpbase[0]);
  const float rpR = bf2f(rpbase[256]);

  float m_s = -3.0e38f, l_s = 0.f;
  f32x4 oacc[4];
#pragma unroll
  for (int ct = 0; ct < 4; ++ct) oacc[ct] = (f32x4){0.f, 0.f, 0.f, 0.f};

  const unsigned short* kbase = kbuf + (size_t)bh * SEQ * HDIM;
  const unsigned short* vbase = vtb + (size_t)bh * HDIM * SEQ;

  for (int jt = 0; jt < 16; ++jt) {
    const int jb = jt * 128;
#pragma unroll
    for (int it = 0; it < 4; ++it) {
      int ch = it * 256 + tid;
      int rk = ch >> 3, clk = (ch & 7) ^ (rk & 7);
      gl2lds16(kbase + (size_t)(jb + rk) * HDIM + clk * 8, Ks + ch * 8);
      int rv = ch >> 4, cv = ch & 15;
      int clv = (cv & 8) | ((cv & 7) ^ (rv & 7));
      gl2lds16(vbase + (size_t)rv * SEQ + jb + clv * 8, Vs + ch * 8);
    }
    __syncthreads();

#pragma unroll
    for (int jh = 0; jh < 2; ++jh) {
      const int j0 = jb + jh * 64;
      const int jrb = jh * 64;   // row base in Ks / col base chunk in Vs

      // S^T = K Q^T : sacc[ct] holds S[j = j0+ct*16+q4*4+reg][i = l16's row]
      f32x4 sacc[4];
#pragma unroll
      for (int ct = 0; ct < 4; ++ct) {
        sacc[ct] = (f32x4){0.f, 0.f, 0.f, 0.f};
        const unsigned short* krow = Ks + (jrb + ct * 16 + l16) * 64;
        bfrag k0f = *(const bfrag*)(krow + (q4 ^ sw) * 8);
        bfrag k1f = *(const bfrag*)(krow + ((4 + q4) ^ sw) * 8);
        sacc[ct] = MFMA16(k0f, qf0, sacc[ct]);
        sacc[ct] = MFMA16(k1f, qf1, sacc[ct]);
      }

      // logits2 = S*(log2e/8) + pos2
      float p[4][4];
      const int dj = j0 - i0;
      if (dj >= 191) {
#pragma unroll
        for (int ct = 0; ct < 4; ++ct)
#pragma unroll
          for (int reg = 0; reg < 4; ++reg)
            p[ct][reg] = sacc[ct][reg] * SC + rpR;
      } else if (dj <= -191) {
#pragma unroll
        for (int ct = 0; ct < 4; ++ct)
#pragma unroll
          for (int reg = 0; reg < 4; ++reg)
            p[ct][reg] = sacc[ct][reg] * SC + rpL;
      } else {
#pragma unroll
        for (int ct = 0; ct < 4; ++ct) {
#pragma unroll
          for (int reg = 0; reg < 4; ++reg) {
            int j = j0 + ct * 16 + q4 * 4 + reg;
            int off = j - ig;
            off = (off < -128) ? -128 : (off > 128 ? 128 : off);
            p[ct][reg] = sacc[ct][reg] * SC + bf2f(rpbase[off + 128]);
          }
        }
      }

      // online softmax: in-lane tree + xor16/xor32
      float mm;
      {
        float a0 = fmaxf(fmaxf(p[0][0], p[0][1]), fmaxf(p[0][2], p[0][3]));
        float a1 = fmaxf(fmaxf(p[1][0], p[1][1]), fmaxf(p[1][2], p[1][3]));
        float a2 = fmaxf(fmaxf(p[2][0], p[2][1]), fmaxf(p[2][2], p[2][3]));
        float a3 = fmaxf(fmaxf(p[3][0], p[3][1]), fmaxf(p[3][2], p[3][3]));
        mm = fmaxf(fmaxf(a0, a1), fmaxf(a2, a3));
        mm = fmaxf(mm, __shfl_xor(mm, 16));
        mm = fmaxf(mm, __shfl_xor(mm, 32));
      }
      const float mnew = fmaxf(m_s, mm);
      const float alpha = fexp2(m_s - mnew);
      m_s = mnew;
#pragma unroll
      for (int ct = 0; ct < 4; ++ct)
#pragma unroll
        for (int reg = 0; reg < 4; ++reg)
          p[ct][reg] = fexp2(p[ct][reg] - m_s);
      {
        float s0 = (p[0][0] + p[0][1]) + (p[0][2] + p[0][3]);
        float s1 = (p[1][0] + p[1][1]) + (p[1][2] + p[1][3]);
        float s2 = (p[2][0] + p[2][1]) + (p[2][2] + p[2][3]);
        float s3 = (p[3][0] + p[3][1]) + (p[3][2] + p[3][3]);
        float rs = (s0 + s1) + (s2 + s3);
        rs += __shfl_xor(rs, 16);
        rs += __shfl_xor(rs, 32);
        l_s = l_s * alpha + rs;
      }
#pragma unroll
      for (int ct = 0; ct < 4; ++ct)
#pragma unroll
        for (int reg = 0; reg < 4; ++reg)
          oacc[ct][reg] *= alpha;

      // P^T -> Ps[i][j-half] packed b32, swizzled; wave-private rows.
      unsigned int* Pw = (unsigned int*)Ps;
#pragma unroll
      for (int ct = 0; ct < 4; ++ct) {
        unsigned int pk01 = pkbf(p[ct][0], p[ct][1]);
        unsigned int pk23 = pkbf(p[ct][2], p[ct][3]);
        int chunk = ct * 2 + (q4 >> 1);
        unsigned int a = rloc * 32 + ((chunk ^ sw) << 2) + ((q4 & 1) << 1);
        Pw[a] = pk01;
        Pw[a + 1] = pk23;
      }

      // PV: out^T += V^T P^T
      bfrag pf0 = *(const bfrag*)(Ps + rloc * 64 + (q4 ^ sw) * 8);
      bfrag pf1 = *(const bfrag*)(Ps + rloc * 64 + ((4 + q4) ^ sw) * 8);
      const int c0 = jh * 8 + q4;
      const int c1 = jh * 8 + 4 + q4;
      const int p0 = (c0 & 8) | ((c0 & 7) ^ sw);
      const int p1 = (c1 & 8) | ((c1 & 7) ^ sw);
#pragma unroll
      for (int ct = 0; ct < 4; ++ct) {
        const unsigned short* vrow = Vs + (ct * 16 + l16) * 128;
        bfrag v0f = *(const bfrag*)(vrow + p0 * 8);
        bfrag v1f = *(const bfrag*)(vrow + p1 * 8);
        oacc[ct] = MFMA16(v0f, pf0, oacc[ct]);
        oacc[ct] = MFMA16(v1f, pf1, oacc[ct]);
      }
    }
    __syncthreads();
  }

  const int bidx = bh >> 4, hh = bh & 15;
  const float inv = 1.0f / l_s;
  float* orow = out + ((size_t)bidx * SEQ + ig) * DMOD + hh * HDIM;
#pragma unroll
  for (int ct = 0; ct < 4; ++ct) {
    float4 v;
    v.x = oacc[ct][0] * inv;
    v.y = oacc[ct][1] * inv;
    v.z = oacc[ct][2] * inv;
    v.w = oacc[ct][3] * inv;
    *(float4*)(orow + ct * 16 + q4 * 4) = v;
  }
}

// ------------------- launch -------------------
extern "C" void kernel_launch(void* const* d_in, const int* in_sizes, int n_in,
                              void* d_out, int out_size, void* d_ws, size_t ws_size,
                              hipStream_t stream) {
  const float* x    = (const float*)d_in[0];  // [2,2048,1024]
  const float* Wqkv = (const float*)d_in[1];  // [3072,1024]
  const float* bqkv = (const float*)d_in[2];  // [3072]
  const float* Wr   = (const float*)d_in[3];  // [257,64]
  const float* br   = (const float*)d_in[4];  // [257]
  float* out = (float*)d_out;                 // [2,2048,1024] fp32

  char* ws = (char*)d_ws;
  unsigned short* xb   = (unsigned short*)(ws);               // 8 MB
  unsigned short* wb   = (unsigned short*)(ws + 8388608);     // 6 MB
  unsigned short* qb   = (unsigned short*)(ws + 14680064);    // 8 MB
  unsigned short* kb   = (unsigned short*)(ws + 23068672);    // 8 MB
  unsigned short* vb   = (unsigned short*)(ws + 31457280);    // 8 MB
  unsigned short* vtb  = (unsigned short*)(ws + 39845888);    // 8 MB
  unsigned short* wrb  = (unsigned short*)(ws + 48234496);    // 34816 B
  unsigned short* rp16 = (unsigned short*)(ws + 48269312);    // 33.7 MB (bf16, ×log2e)

  cast_all<<<7185, 256, 0, stream>>>(x, Wqkv, Wr, xb, wb, wrb);
  qkv_gemm<<<dim3(24, 32), 256, 0, stream>>>(xb, wb, bqkv, qb, kb, vb);
  vtrans<<<dim3(32, 32), 256, 0, stream>>>(vb, vtb);
  rp_gemm<<<1024, 256, 0, stream>>>(qb, wrb, br, rp16);
  flash_attn<<<dim3(32, 32), 256, 0, stream>>>(qb, kb, vtb, rp16, out);
}

// Round 7
// 232.448 us; speedup vs baseline: 1.0614x; 1.0614x over previous
//
#include <hip/hip_runtime.h>

typedef short bfrag __attribute__((ext_vector_type(8)));   // 8 bf16 (4 VGPRs)
typedef float f32x4 __attribute__((ext_vector_type(4)));   // MFMA accumulator

#define MFMA16(a, b, c) __builtin_amdgcn_mfma_f32_16x16x32_bf16((a), (b), (c), 0, 0, 0)

// b=2, s=2048, d=1024, h=16, hd=64, R=257, w=128, scale=sqrt(64)=8
#define SEQ   2048
#define DMOD  1024
#define NHEAD 16
#define HDIM  64
#define RSZ   257
#define RPADN 272     // 17*16, zero-padded
#define XN    (4096*1024)
#define WN    (3072*1024)
#define LOG2E 1.44269504f

__device__ __forceinline__ unsigned short f2bf(float f) {
  unsigned int u = __float_as_uint(f);
  u += 0x7FFFu + ((u >> 16) & 1u);   // round-to-nearest-even
  return (unsigned short)(u >> 16);
}
__device__ __forceinline__ float bf2f(unsigned short u) {
  return __uint_as_float(((unsigned int)u) << 16);
}
// packed f32x2 -> bf16x2 (single v_cvt_pk_bf16_f32 on gfx950)
__device__ __forceinline__ unsigned int pkbf(float a, float b) {
#if defined(__gfx950__)
  unsigned int r;
  asm("v_cvt_pk_bf16_f32 %0, %1, %2" : "=v"(r) : "v"(a), "v"(b));
  return r;
#else
  return (unsigned int)f2bf(a) | ((unsigned int)f2bf(b) << 16);
#endif
}
__device__ __forceinline__ float fexp2(float x) {
#if __has_builtin(__builtin_amdgcn_exp2f)
  return __builtin_amdgcn_exp2f(x);
#else
  return __expf(x * 0.69314718f);
#endif
}
__device__ __forceinline__ void gl2lds16(const void* g, void* l) {
  __builtin_amdgcn_global_load_lds(
      (__attribute__((address_space(1))) void*)(g),
      (__attribute__((address_space(3))) void*)(l), 16, 0, 0);
}

// ------------------- fused cast kernel -------------------
__global__ __launch_bounds__(256) void cast_all(const float* __restrict__ x,
                                                const float* __restrict__ Wqkv,
                                                const float* __restrict__ Wr,
                                                unsigned short* __restrict__ xb,
                                                unsigned short* __restrict__ wb,
                                                unsigned short* __restrict__ wrb) {
  int i = (blockIdx.x * 256 + threadIdx.x) * 4;
  if (i < XN) {
    float4 v = *(const float4*)(x + i);
    ushort4 o; o.x = f2bf(v.x); o.y = f2bf(v.y); o.z = f2bf(v.z); o.w = f2bf(v.w);
    *(ushort4*)(xb + i) = o;
  } else if (i < XN + WN) {
    int j = i - XN;
    float4 v = *(const float4*)(Wqkv + j);
    ushort4 o; o.x = f2bf(v.x); o.y = f2bf(v.y); o.z = f2bf(v.z); o.w = f2bf(v.w);
    *(ushort4*)(wb + j) = o;
  } else {
    int j = i - XN - WN;      // 0 .. 17407, 4 at a time
    ushort4 o;
    unsigned short t[4];
#pragma unroll
    for (int k = 0; k < 4; ++k)
      t[k] = (j + k < RSZ * HDIM) ? f2bf(Wr[j + k]) : (unsigned short)0;
    o.x = t[0]; o.y = t[1]; o.z = t[2]; o.w = t[3];
    *(ushort4*)(wrb + j) = o;
  }
}

// ------------------- QKV projection GEMM -------------------
// 128x128 tile, BK=64. Epilogue: C -> LDS (swizzled) -> coalesced 16B stores
// into qb/kbuf (row-major) and vtb (TRANSPOSED [bh][d][s], read cols from LDS).
__global__ __launch_bounds__(256) void qkv_gemm(const unsigned short* __restrict__ xb,
                                                const unsigned short* __restrict__ wb,
                                                const float* __restrict__ bqkv,
                                                unsigned short* __restrict__ qb,
                                                unsigned short* __restrict__ kbuf,
                                                unsigned short* __restrict__ vtb) {
  __shared__ unsigned short SMEM[2 * 128 * 64];   // As | Bs, reused as C 128x128
  unsigned short* As = SMEM;
  unsigned short* Bs = SMEM + 128 * 64;
  const int tid = threadIdx.x;
  const int m0 = blockIdx.y * 128, n0 = blockIdx.x * 128;
  const int wave = tid >> 6, lane = tid & 63;
  const int q4 = lane >> 4, l16 = lane & 15;
  const int wm = (wave & 1) * 64, wn = (wave >> 1) * 64;
  const int sw = l16 & 7;

  f32x4 acc[4][4];
#pragma unroll
  for (int rt = 0; rt < 4; ++rt)
#pragma unroll
    for (int ct = 0; ct < 4; ++ct) acc[rt][ct] = (f32x4){0.f, 0.f, 0.f, 0.f};

  for (int k0 = 0; k0 < DMOD; k0 += 64) {
#pragma unroll
    for (int it = 0; it < 4; ++it) {
      int ch = it * 256 + tid;
      int r = ch >> 3, cl = (ch & 7) ^ (r & 7);
      gl2lds16(xb + (size_t)(m0 + r) * DMOD + k0 + cl * 8, As + ch * 8);
      gl2lds16(wb + (size_t)(n0 + r) * DMOD + k0 + cl * 8, Bs + ch * 8);
    }
    __syncthreads();
#pragma unroll
    for (int ks = 0; ks < 2; ++ks) {
      bfrag af[4], bf[4];
#pragma unroll
      for (int rt = 0; rt < 4; ++rt)
        af[rt] = *(const bfrag*)(As + (wm + rt * 16 + l16) * 64 + ((ks * 4 + q4) ^ sw) * 8);
#pragma unroll
      for (int ct = 0; ct < 4; ++ct)
        bf[ct] = *(const bfrag*)(Bs + (wn + ct * 16 + l16) * 64 + ((ks * 4 + q4) ^ sw) * 8);
#pragma unroll
      for (int rt = 0; rt < 4; ++rt)
#pragma unroll
        for (int ct = 0; ct < 4; ++ct)
          acc[rt][ct] = MFMA16(af[rt], bf[ct], acc[rt][ct]);
    }
    __syncthreads();
  }

  // ---- epilogue phase 1: C -> LDS, chunk-swizzled per row ----
  unsigned short* Cs = SMEM;   // 128 x 128 bf16
#pragma unroll
  for (int rt = 0; rt < 4; ++rt) {
#pragma unroll
    for (int ct = 0; ct < 4; ++ct) {
      int n = wn + ct * 16 + l16;        // tile-local col 0..127
      float bias = bqkv[n0 + n];
      int c = n >> 3, nl = n & 7;
#pragma unroll
      for (int reg = 0; reg < 4; ++reg) {
        int m = wm + rt * 16 + q4 * 4 + reg;
        int s = ((m >> 3) ^ m) & 7;
        Cs[m * 128 + ((c ^ s) << 3) + nl] = f2bf(acc[rt][ct][reg] + bias);
      }
    }
  }
  __syncthreads();

  const int batch = m0 >> 11;          // constant per block (128 | 2048)
  const int sbase = m0 & 2047;
  const int r3 = blockIdx.x % 3;       // V-region pattern: period 3 tiles
  const bool hasV = (r3 != 0);
  const int nv0 = n0 + ((r3 == 2) ? 64 : 0);   // global col base of V region

  // ---- phase 2a: q/k chunks -> coalesced row stores ----
#pragma unroll
  for (int it = 0; it < 8; ++it) {
    int idx = it * 256 + tid;
    int r = idx >> 4, c = idx & 15;      // row 0..127, chunk 0..15
    int ng = n0 + c * 8;
    int hh = ng / 192;
    int rem = ng - hh * 192;
    int t = rem >> 6, dd = rem & 63;
    if (t == 2) continue;                // V handled transposed below
    int s = ((r >> 3) ^ r) & 7;
    bfrag val = *(const bfrag*)(Cs + r * 128 + (((c & 8) | ((c & 7) ^ s)) << 3));
    size_t o = (((size_t)(batch * NHEAD + hh)) * SEQ + (sbase + r)) * HDIM + dd;
    unsigned short* dst = (t == 0) ? qb : kbuf;
    *(bfrag*)(dst + o) = val;
  }

  // ---- phase 2b: V region (64 cols) -> transposed 16B stores into vtb ----
  if (hasV) {
    const int hh = nv0 / 192;
    unsigned short* vdst = vtb + ((size_t)(batch * NHEAD + hh)) * HDIM * SEQ;
    const int cbase = nv0 - n0;          // tile-local col base of V (0 or 64)
#pragma unroll
    for (int it = 0; it < 4; ++it) {
      int u = it * 256 + tid;            // 1024 units: dd in [0,64), rc in [0,16)
      int dd = u >> 4, rc = u & 15;
      int nloc = cbase + dd;
      int c = nloc >> 3, nl = nloc & 7;
      unsigned short tmp[8];
#pragma unroll
      for (int k = 0; k < 8; ++k) {
        int m = rc * 8 + k;
        int s = ((m >> 3) ^ m) & 7;
        tmp[k] = Cs[m * 128 + (((c & 8) | ((c & 7) ^ s)) << 3) + nl];
      }
      *(uint4*)(vdst + (size_t)dd * SEQ + sbase + rc * 8) = *(uint4*)tmp;
    }
  }
}

// ------------------- rel-pos logits (pre-scaled by log2e, bf16 out) -------
__global__ __launch_bounds__(256) void rp_gemm(const unsigned short* __restrict__ qb,
                                               const unsigned short* __restrict__ wrb,
                                               const float* __restrict__ br,
                                               unsigned short* __restrict__ rp16) {
  __shared__ unsigned short WrS[RPADN * HDIM];  // 34816 B
  __shared__ unsigned short Qs[64 * HDIM];      // 8192 B
  const int tid = threadIdx.x;
  const size_t row0 = (size_t)blockIdx.x * 64;

  for (int i = tid; i < RPADN * HDIM / 8; i += 256)
    *(uint4*)(&WrS[i * 8]) = *(const uint4*)(&wrb[i * 8]);
  for (int i = tid; i < 512; i += 256)
    *(uint4*)(&Qs[i * 8]) = *(const uint4*)(&qb[row0 * HDIM + i * 8]);
  __syncthreads();

  const int wave = tid >> 6, lane = tid & 63;
  const int q4 = lane >> 4, l16 = lane & 15;

  bfrag af0 = *(const bfrag*)(Qs + (wave * 16 + l16) * 64 + q4 * 8);
  bfrag af1 = *(const bfrag*)(Qs + (wave * 16 + l16) * 64 + 32 + q4 * 8);

#pragma unroll 4
  for (int ct = 0; ct < 17; ++ct) {
    f32x4 acc = (f32x4){0.f, 0.f, 0.f, 0.f};
    bfrag b0 = *(const bfrag*)(WrS + (ct * 16 + l16) * 64 + q4 * 8);
    bfrag b1 = *(const bfrag*)(WrS + (ct * 16 + l16) * 64 + 32 + q4 * 8);
    acc = MFMA16(af0, b0, acc);
    acc = MFMA16(af1, b1, acc);
    int col = ct * 16 + l16;
    if (col < RSZ) {
      float bias = br[col];
#pragma unroll
      for (int reg = 0; reg < 4; ++reg) {
        size_t rr = row0 + wave * 16 + q4 * 4 + reg;
        rp16[rr * RSZ + col] = f2bf((acc[reg] + bias) * LOG2E);
      }
    }
  }
}

// ------------------- flash attention, transposed-S formulation ------------
// (round-5 measured optimum: BN=64, 24.5 KB LDS, 1 staging barrier + 1 tail)
__global__ __launch_bounds__(256) void flash_attn(const unsigned short* __restrict__ qb,
                                                  const unsigned short* __restrict__ kbuf,
                                                  const unsigned short* __restrict__ vtb,
                                                  const unsigned short* __restrict__ rp16,
                                                  float* __restrict__ out) {
  __shared__ unsigned short Ks[64 * 64];
  __shared__ unsigned short Vs[64 * 64];   // [d][j]
  __shared__ unsigned short Ps[64 * 64];   // P[i][j], chunk-swizzled per row

  const int tid = threadIdx.x;
  const int i0 = blockIdx.x * 64;
  const int bh = blockIdx.y;
  const int wave = tid >> 6, lane = tid & 63;
  const int q4 = lane >> 4, l16 = lane & 15;
  const int sw = l16 & 7;
  const float SC = 0.125f * LOG2E;

  const int rloc = wave * 16 + l16;
  const int ig = i0 + rloc;                 // this lane's global Q row
  const unsigned short* qrow = qb + ((size_t)bh * SEQ + ig) * HDIM;
  bfrag qf0 = *(const bfrag*)(qrow + q4 * 8);
  bfrag qf1 = *(const bfrag*)(qrow + 32 + q4 * 8);

  const unsigned short* rpbase = rp16 + ((size_t)bh * SEQ + ig) * RSZ;
  const float rpL = bf2f(rpbase[0]);
  const float rpR = bf2f(rpbase[256]);

  float m_s = -3.0e38f, l_s = 0.f;
  f32x4 oacc[4];
#pragma unroll
  for (int ct = 0; ct < 4; ++ct) oacc[ct] = (f32x4){0.f, 0.f, 0.f, 0.f};

  const unsigned short* kbase = kbuf + (size_t)bh * SEQ * HDIM;
  const unsigned short* vbase = vtb + (size_t)bh * HDIM * SEQ;

  for (int jt = 0; jt < 32; ++jt) {
    const int j0 = jt * 64;
#pragma unroll
    for (int it = 0; it < 2; ++it) {
      int ch = it * 256 + tid;
      int r = ch >> 3, cl = (ch & 7) ^ (r & 7);
      gl2lds16(kbase + (size_t)(j0 + r) * HDIM + cl * 8, Ks + ch * 8);
      gl2lds16(vbase + (size_t)r * SEQ + j0 + cl * 8, Vs + ch * 8);
    }
    __syncthreads();

    // S^T = K Q^T : sacc[ct] holds S[j = ct*16+q4*4+reg][i = l16's row]
    f32x4 sacc[4];
#pragma unroll
    for (int ct = 0; ct < 4; ++ct) {
      sacc[ct] = (f32x4){0.f, 0.f, 0.f, 0.f};
      bfrag k0f = *(const bfrag*)(Ks + (ct * 16 + l16) * 64 + (q4 ^ sw) * 8);
      bfrag k1f = *(const bfrag*)(Ks + (ct * 16 + l16) * 64 + ((4 + q4) ^ sw) * 8);
      sacc[ct] = MFMA16(k0f, qf0, sacc[ct]);
      sacc[ct] = MFMA16(k1f, qf1, sacc[ct]);
    }

    // logits2 = S*(log2e/8) + pos2 ; all 16 of this lane's row in-register
    float p[4][4];
    const int dj = j0 - i0;
    if (dj >= 191) {
#pragma unroll
      for (int ct = 0; ct < 4; ++ct)
#pragma unroll
        for (int reg = 0; reg < 4; ++reg)
          p[ct][reg] = sacc[ct][reg] * SC + rpR;
    } else if (dj <= -191) {
#pragma unroll
      for (int ct = 0; ct < 4; ++ct)
#pragma unroll
        for (int reg = 0; reg < 4; ++reg)
          p[ct][reg] = sacc[ct][reg] * SC + rpL;
    } else {
#pragma unroll
      for (int ct = 0; ct < 4; ++ct) {
#pragma unroll
        for (int reg = 0; reg < 4; ++reg) {
          int j = j0 + ct * 16 + q4 * 4 + reg;
          int off = j - ig;
          off = (off < -128) ? -128 : (off > 128 ? 128 : off);
          p[ct][reg] = sacc[ct][reg] * SC + bf2f(rpbase[off + 128]);
        }
      }
    }

    // online softmax: in-lane tree + xor16/xor32 (quads hold disjoint j's)
    float mm;
    {
      float a0 = fmaxf(fmaxf(p[0][0], p[0][1]), fmaxf(p[0][2], p[0][3]));
      float a1 = fmaxf(fmaxf(p[1][0], p[1][1]), fmaxf(p[1][2], p[1][3]));
      float a2 = fmaxf(fmaxf(p[2][0], p[2][1]), fmaxf(p[2][2], p[2][3]));
      float a3 = fmaxf(fmaxf(p[3][0], p[3][1]), fmaxf(p[3][2], p[3][3]));
      mm = fmaxf(fmaxf(a0, a1), fmaxf(a2, a3));
      mm = fmaxf(mm, __shfl_xor(mm, 16));
      mm = fmaxf(mm, __shfl_xor(mm, 32));
    }
    const float mnew = fmaxf(m_s, mm);
    const float alpha = fexp2(m_s - mnew);
    m_s = mnew;
#pragma unroll
    for (int ct = 0; ct < 4; ++ct)
#pragma unroll
      for (int reg = 0; reg < 4; ++reg)
        p[ct][reg] = fexp2(p[ct][reg] - m_s);
    {
      float s0 = (p[0][0] + p[0][1]) + (p[0][2] + p[0][3]);
      float s1 = (p[1][0] + p[1][1]) + (p[1][2] + p[1][3]);
      float s2 = (p[2][0] + p[2][1]) + (p[2][2] + p[2][3]);
      float s3 = (p[3][0] + p[3][1]) + (p[3][2] + p[3][3]);
      float rs = (s0 + s1) + (s2 + s3);
      rs += __shfl_xor(rs, 16);
      rs += __shfl_xor(rs, 32);
      l_s = l_s * alpha + rs;
    }
#pragma unroll
    for (int ct = 0; ct < 4; ++ct)
#pragma unroll
      for (int reg = 0; reg < 4; ++reg)
        oacc[ct][reg] *= alpha;

    // P^T (C-layout) -> Ps[i][j] as packed b32, chunk-swizzled (2-way free).
    unsigned int* Pw = (unsigned int*)Ps;
#pragma unroll
    for (int ct = 0; ct < 4; ++ct) {
      unsigned int pk01 = pkbf(p[ct][0], p[ct][1]);
      unsigned int pk23 = pkbf(p[ct][2], p[ct][3]);
      int chunk = ct * 2 + (q4 >> 1);
      unsigned int a = rloc * 32 + ((chunk ^ sw) << 2) + ((q4 & 1) << 1);
      Pw[a] = pk01;
      Pw[a + 1] = pk23;
    }

    // PV: out^T += V^T P^T ; pf = B-frag rows = Q rows (read own row)
    bfrag pf0 = *(const bfrag*)(Ps + rloc * 64 + (q4 ^ sw) * 8);
    bfrag pf1 = *(const bfrag*)(Ps + rloc * 64 + ((4 + q4) ^ sw) * 8);
#pragma unroll
    for (int ct = 0; ct < 4; ++ct) {
      bfrag v0f = *(const bfrag*)(Vs + (ct * 16 + l16) * 64 + (q4 ^ sw) * 8);
      bfrag v1f = *(const bfrag*)(Vs + (ct * 16 + l16) * 64 + ((4 + q4) ^ sw) * 8);
      oacc[ct] = MFMA16(v0f, pf0, oacc[ct]);
      oacc[ct] = MFMA16(v1f, pf1, oacc[ct]);
    }
    __syncthreads();
  }

  const int bidx = bh >> 4, hh = bh & 15;
  const float inv = 1.0f / l_s;
  float* orow = out + ((size_t)bidx * SEQ + ig) * DMOD + hh * HDIM;
#pragma unroll
  for (int ct = 0; ct < 4; ++ct) {
    float4 v;
    v.x = oacc[ct][0] * inv;
    v.y = oacc[ct][1] * inv;
    v.z = oacc[ct][2] * inv;
    v.w = oacc[ct][3] * inv;
    *(float4*)(orow + ct * 16 + q4 * 4) = v;
  }
}

// ------------------- launch -------------------
extern "C" void kernel_launch(void* const* d_in, const int* in_sizes, int n_in,
                              void* d_out, int out_size, void* d_ws, size_t ws_size,
                              hipStream_t stream) {
  const float* x    = (const float*)d_in[0];  // [2,2048,1024]
  const float* Wqkv = (const float*)d_in[1];  // [3072,1024]
  const float* bqkv = (const float*)d_in[2];  // [3072]
  const float* Wr   = (const float*)d_in[3];  // [257,64]
  const float* br   = (const float*)d_in[4];  // [257]
  float* out = (float*)d_out;                 // [2,2048,1024] fp32

  char* ws = (char*)d_ws;
  unsigned short* xb   = (unsigned short*)(ws);               // 8 MB
  unsigned short* wb   = (unsigned short*)(ws + 8388608);     // 6 MB
  unsigned short* qb   = (unsigned short*)(ws + 14680064);    // 8 MB
  unsigned short* kb   = (unsigned short*)(ws + 23068672);    // 8 MB
  unsigned short* vtb  = (unsigned short*)(ws + 31457280);    // 8 MB (transposed V)
  unsigned short* wrb  = (unsigned short*)(ws + 39845888);    // 34816 B
  unsigned short* rp16 = (unsigned short*)(ws + 39880704);    // 33.7 MB (bf16, ×log2e)

  cast_all<<<7185, 256, 0, stream>>>(x, Wqkv, Wr, xb, wb, wrb);
  qkv_gemm<<<dim3(24, 32), 256, 0, stream>>>(xb, wb, bqkv, qb, kb, vtb);
  rp_gemm<<<1024, 256, 0, stream>>>(qb, wrb, br, rp16);
  flash_attn<<<dim3(32, 32), 256, 0, stream>>>(qb, kb, vtb, rp16, out);
}

// Round 8
// 225.241 us; speedup vs baseline: 1.0954x; 1.0320x over previous
//
#include <hip/hip_runtime.h>

typedef short bfrag __attribute__((ext_vector_type(8)));   // 8 bf16 (4 VGPRs)
typedef float f32x4 __attribute__((ext_vector_type(4)));   // MFMA accumulator

#define MFMA16(a, b, c) __builtin_amdgcn_mfma_f32_16x16x32_bf16((a), (b), (c), 0, 0, 0)

// b=2, s=2048, d=1024, h=16, hd=64, R=257, w=128, scale=sqrt(64)=8
#define SEQ   2048
#define DMOD  1024
#define NHEAD 16
#define HDIM  64
#define RSZ   257
#define RSTRIDE 260   // padded row stride of rp16 (8B-aligned vector stores)
#define RPADN 272     // 17*16, zero-padded
#define XN    (4096*1024)
#define WN    (3072*1024)
#define LOG2E 1.44269504f

__device__ __forceinline__ unsigned short f2bf(float f) {
  unsigned int u = __float_as_uint(f);
  u += 0x7FFFu + ((u >> 16) & 1u);   // round-to-nearest-even
  return (unsigned short)(u >> 16);
}
__device__ __forceinline__ float bf2f(unsigned short u) {
  return __uint_as_float(((unsigned int)u) << 16);
}
// packed f32x2 -> bf16x2 (single v_cvt_pk_bf16_f32 on gfx950)
__device__ __forceinline__ unsigned int pkbf(float a, float b) {
#if defined(__gfx950__)
  unsigned int r;
  asm("v_cvt_pk_bf16_f32 %0, %1, %2" : "=v"(r) : "v"(a), "v"(b));
  return r;
#else
  return (unsigned int)f2bf(a) | ((unsigned int)f2bf(b) << 16);
#endif
}
__device__ __forceinline__ float fexp2(float x) {
#if __has_builtin(__builtin_amdgcn_exp2f)
  return __builtin_amdgcn_exp2f(x);
#else
  return __expf(x * 0.69314718f);
#endif
}
__device__ __forceinline__ void gl2lds16(const void* g, void* l) {
  __builtin_amdgcn_global_load_lds(
      (__attribute__((address_space(1))) void*)(g),
      (__attribute__((address_space(3))) void*)(l), 16, 0, 0);
}

// ------------------- fused cast kernel -------------------
__global__ __launch_bounds__(256) void cast_all(const float* __restrict__ x,
                                                const float* __restrict__ Wqkv,
                                                const float* __restrict__ Wr,
                                                unsigned short* __restrict__ xb,
                                                unsigned short* __restrict__ wb,
                                                unsigned short* __restrict__ wrb) {
  int i = (blockIdx.x * 256 + threadIdx.x) * 4;
  if (i < XN) {
    float4 v = *(const float4*)(x + i);
    ushort4 o; o.x = f2bf(v.x); o.y = f2bf(v.y); o.z = f2bf(v.z); o.w = f2bf(v.w);
    *(ushort4*)(xb + i) = o;
  } else if (i < XN + WN) {
    int j = i - XN;
    float4 v = *(const float4*)(Wqkv + j);
    ushort4 o; o.x = f2bf(v.x); o.y = f2bf(v.y); o.z = f2bf(v.z); o.w = f2bf(v.w);
    *(ushort4*)(wb + j) = o;
  } else {
    int j = i - XN - WN;      // 0 .. 17407, 4 at a time
    ushort4 o;
    unsigned short t[4];
#pragma unroll
    for (int k = 0; k < 4; ++k)
      t[k] = (j + k < RSZ * HDIM) ? f2bf(Wr[j + k]) : (unsigned short)0;
    o.x = t[0]; o.y = t[1]; o.z = t[2]; o.w = t[3];
    *(ushort4*)(wrb + j) = o;
  }
}

// ------------------- QKV projection GEMM -------------------
// 128x128 tile, BK=64. MFMA operand order swapped (bf, af): lane holds
// m = wm+rt*16+l16 fixed and 4 consecutive n in regs -> direct 8B stores
// for q/k; V region through a small LDS tile for transposed 16B stores.
__global__ __launch_bounds__(256) void qkv_gemm(const unsigned short* __restrict__ xb,
                                                const unsigned short* __restrict__ wb,
                                                const float* __restrict__ bqkv,
                                                unsigned short* __restrict__ qb,
                                                unsigned short* __restrict__ kbuf,
                                                unsigned short* __restrict__ vtb) {
  __shared__ unsigned short SMEM[2 * 128 * 64];   // As | Bs; reused as Vtmp
  unsigned short* As = SMEM;
  unsigned short* Bs = SMEM + 128 * 64;
  unsigned short* Vtmp = SMEM;                    // 64 x 136 bf16 (17408 B)
  const int tid = threadIdx.x;
  const int m0 = blockIdx.y * 128, n0 = blockIdx.x * 128;
  const int wave = tid >> 6, lane = tid & 63;
  const int q4 = lane >> 4, l16 = lane & 15;
  const int wm = (wave & 1) * 64, wn = (wave >> 1) * 64;
  const int sw = l16 & 7;

  f32x4 acc[4][4];
#pragma unroll
  for (int rt = 0; rt < 4; ++rt)
#pragma unroll
    for (int ct = 0; ct < 4; ++ct) acc[rt][ct] = (f32x4){0.f, 0.f, 0.f, 0.f};

  for (int k0 = 0; k0 < DMOD; k0 += 64) {
#pragma unroll
    for (int it = 0; it < 4; ++it) {
      int ch = it * 256 + tid;
      int r = ch >> 3, cl = (ch & 7) ^ (r & 7);
      gl2lds16(xb + (size_t)(m0 + r) * DMOD + k0 + cl * 8, As + ch * 8);
      gl2lds16(wb + (size_t)(n0 + r) * DMOD + k0 + cl * 8, Bs + ch * 8);
    }
    __syncthreads();
#pragma unroll
    for (int ks = 0; ks < 2; ++ks) {
      bfrag af[4], bf[4];
#pragma unroll
      for (int rt = 0; rt < 4; ++rt)
        af[rt] = *(const bfrag*)(As + (wm + rt * 16 + l16) * 64 + ((ks * 4 + q4) ^ sw) * 8);
#pragma unroll
      for (int ct = 0; ct < 4; ++ct)
        bf[ct] = *(const bfrag*)(Bs + (wn + ct * 16 + l16) * 64 + ((ks * 4 + q4) ^ sw) * 8);
      // swapped order: D rows <- bf rows (n), D cols <- af rows (m)
#pragma unroll
      for (int rt = 0; rt < 4; ++rt)
#pragma unroll
        for (int ct = 0; ct < 4; ++ct)
          acc[rt][ct] = MFMA16(bf[ct], af[rt], acc[rt][ct]);
    }
    __syncthreads();
  }

  // ---- epilogue: lane holds C[m][n..n+3]; m = wm+rt*16+l16, n = wn+ct*16+q4*4
  const int batch = m0 >> 11;
  const int sbase = m0 & 2047;
  const int r3 = blockIdx.x % 3;       // V-region pattern: period 3 tiles
  const bool hasV = (r3 != 0);
  const int nv0 = n0 + ((r3 == 2) ? 64 : 0);   // global col base of V region

#pragma unroll
  for (int ct = 0; ct < 4; ++ct) {
    int ng = n0 + wn + ct * 16 + q4 * 4;
    int hh = ng / 192;
    int rem = ng - hh * 192;
    int t = rem >> 6, dd = rem & 63;
    float4 b4 = *(const float4*)(bqkv + ng);
    if (t < 2) {
      unsigned short* dst = (t == 0) ? qb : kbuf;
      size_t rowo = ((size_t)(batch * NHEAD + hh)) * SEQ + sbase;
#pragma unroll
      for (int rt = 0; rt < 4; ++rt) {
        int m = wm + rt * 16 + l16;
        uint2 pv;
        pv.x = pkbf(acc[rt][ct][0] + b4.x, acc[rt][ct][1] + b4.y);
        pv.y = pkbf(acc[rt][ct][2] + b4.z, acc[rt][ct][3] + b4.w);
        *(uint2*)(dst + (rowo + m) * HDIM + dd) = pv;
      }
    } else {
#pragma unroll
      for (int rt = 0; rt < 4; ++rt) {
        int m = wm + rt * 16 + l16;
        Vtmp[(dd + 0) * 136 + m] = f2bf(acc[rt][ct][0] + b4.x);
        Vtmp[(dd + 1) * 136 + m] = f2bf(acc[rt][ct][1] + b4.y);
        Vtmp[(dd + 2) * 136 + m] = f2bf(acc[rt][ct][2] + b4.z);
        Vtmp[(dd + 3) * 136 + m] = f2bf(acc[rt][ct][3] + b4.w);
      }
    }
  }

  if (hasV) {
    __syncthreads();
    const int hh = nv0 / 192;
    unsigned short* vdst = vtb + ((size_t)(batch * NHEAD + hh)) * HDIM * SEQ;
#pragma unroll
    for (int it = 0; it < 4; ++it) {
      int u = it * 256 + tid;            // dd in [0,64), mc in [0,16)
      int dd = u >> 4, mc = u & 15;
      bfrag val = *(const bfrag*)(Vtmp + dd * 136 + mc * 8);
      *(bfrag*)(vdst + (size_t)dd * SEQ + sbase + mc * 8) = val;
    }
  }
}

// ------------------- rel-pos logits (transposed-D, vector stores) ---------
// rp16[i][r] = (q[i]·Wr[r] + br[r]) * log2e, bf16, row stride RSTRIDE.
__global__ __launch_bounds__(256) void rp_gemm(const unsigned short* __restrict__ qb,
                                               const unsigned short* __restrict__ wrb,
                                               const float* __restrict__ br,
                                               unsigned short* __restrict__ rp16) {
  __shared__ unsigned short WrS[RPADN * HDIM];  // 34816 B
  __shared__ unsigned short Qs[64 * HDIM];      // 8192 B
  const int tid = threadIdx.x;
  const size_t row0 = (size_t)blockIdx.x * 64;

  for (int i = tid; i < RPADN * HDIM / 8; i += 256)
    *(uint4*)(&WrS[i * 8]) = *(const uint4*)(&wrb[i * 8]);
  for (int i = tid; i < 512; i += 256)
    *(uint4*)(&Qs[i * 8]) = *(const uint4*)(&qb[row0 * HDIM + i * 8]);
  __syncthreads();

  const int wave = tid >> 6, lane = tid & 63;
  const int q4 = lane >> 4, l16 = lane & 15;

  bfrag af0 = *(const bfrag*)(Qs + (wave * 16 + l16) * 64 + q4 * 8);
  bfrag af1 = *(const bfrag*)(Qs + (wave * 16 + l16) * 64 + 32 + q4 * 8);

  unsigned short* rrow = rp16 + (row0 + wave * 16 + l16) * RSTRIDE;
  const float br256 = br[256];

#pragma unroll 4
  for (int ct = 0; ct < 16; ++ct) {
    f32x4 acc = (f32x4){0.f, 0.f, 0.f, 0.f};
    bfrag w0 = *(const bfrag*)(WrS + (ct * 16 + l16) * 64 + q4 * 8);
    bfrag w1 = *(const bfrag*)(WrS + (ct * 16 + l16) * 64 + 32 + q4 * 8);
    // swapped order: D rows <- Wr rows (r), D cols <- q rows (i)
    acc = MFMA16(w0, af0, acc);
    acc = MFMA16(w1, af1, acc);
    int r = ct * 16 + q4 * 4;
    float4 b4 = *(const float4*)(br + r);
    uint2 pv;
    pv.x = pkbf((acc[0] + b4.x) * LOG2E, (acc[1] + b4.y) * LOG2E);
    pv.y = pkbf((acc[2] + b4.z) * LOG2E, (acc[3] + b4.w) * LOG2E);
    *(uint2*)(rrow + r) = pv;
  }
  // tail tile: only r = 256 is a real column
  {
    f32x4 acc = (f32x4){0.f, 0.f, 0.f, 0.f};
    bfrag w0 = *(const bfrag*)(WrS + (256 + l16) * 64 + q4 * 8);
    bfrag w1 = *(const bfrag*)(WrS + (256 + l16) * 64 + 32 + q4 * 8);
    acc = MFMA16(w0, af0, acc);
    acc = MFMA16(w1, af1, acc);
    if (q4 == 0)
      rrow[256] = f2bf((acc[0] + br256) * LOG2E);
  }
}

// ------------------- flash attention, transposed-S formulation ------------
// (round-5 measured optimum: BN=64, 24.5 KB LDS; only rp stride changed)
__global__ __launch_bounds__(256) void flash_attn(const unsigned short* __restrict__ qb,
                                                  const unsigned short* __restrict__ kbuf,
                                                  const unsigned short* __restrict__ vtb,
                                                  const unsigned short* __restrict__ rp16,
                                                  float* __restrict__ out) {
  __shared__ unsigned short Ks[64 * 64];
  __shared__ unsigned short Vs[64 * 64];   // [d][j]
  __shared__ unsigned short Ps[64 * 64];   // P[i][j], chunk-swizzled per row

  const int tid = threadIdx.x;
  const int i0 = blockIdx.x * 64;
  const int bh = blockIdx.y;
  const int wave = tid >> 6, lane = tid & 63;
  const int q4 = lane >> 4, l16 = lane & 15;
  const int sw = l16 & 7;
  const float SC = 0.125f * LOG2E;

  const int rloc = wave * 16 + l16;
  const int ig = i0 + rloc;                 // this lane's global Q row
  const unsigned short* qrow = qb + ((size_t)bh * SEQ + ig) * HDIM;
  bfrag qf0 = *(const bfrag*)(qrow + q4 * 8);
  bfrag qf1 = *(const bfrag*)(qrow + 32 + q4 * 8);

  const unsigned short* rpbase = rp16 + ((size_t)bh * SEQ + ig) * RSTRIDE;
  const float rpL = bf2f(rpbase[0]);
  const float rpR = bf2f(rpbase[256]);

  float m_s = -3.0e38f, l_s = 0.f;
  f32x4 oacc[4];
#pragma unroll
  for (int ct = 0; ct < 4; ++ct) oacc[ct] = (f32x4){0.f, 0.f, 0.f, 0.f};

  const unsigned short* kbase = kbuf + (size_t)bh * SEQ * HDIM;
  const unsigned short* vbase = vtb + (size_t)bh * HDIM * SEQ;

  for (int jt = 0; jt < 32; ++jt) {
    const int j0 = jt * 64;
#pragma unroll
    for (int it = 0; it < 2; ++it) {
      int ch = it * 256 + tid;
      int r = ch >> 3, cl = (ch & 7) ^ (r & 7);
      gl2lds16(kbase + (size_t)(j0 + r) * HDIM + cl * 8, Ks + ch * 8);
      gl2lds16(vbase + (size_t)r * SEQ + j0 + cl * 8, Vs + ch * 8);
    }
    __syncthreads();

    // S^T = K Q^T : sacc[ct] holds S[j = ct*16+q4*4+reg][i = l16's row]
    f32x4 sacc[4];
#pragma unroll
    for (int ct = 0; ct < 4; ++ct) {
      sacc[ct] = (f32x4){0.f, 0.f, 0.f, 0.f};
      bfrag k0f = *(const bfrag*)(Ks + (ct * 16 + l16) * 64 + (q4 ^ sw) * 8);
      bfrag k1f = *(const bfrag*)(Ks + (ct * 16 + l16) * 64 + ((4 + q4) ^ sw) * 8);
      sacc[ct] = MFMA16(k0f, qf0, sacc[ct]);
      sacc[ct] = MFMA16(k1f, qf1, sacc[ct]);
    }

    // logits2 = S*(log2e/8) + pos2 ; all 16 of this lane's row in-register
    float p[4][4];
    const int dj = j0 - i0;
    if (dj >= 191) {
#pragma unroll
      for (int ct = 0; ct < 4; ++ct)
#pragma unroll
        for (int reg = 0; reg < 4; ++reg)
          p[ct][reg] = sacc[ct][reg] * SC + rpR;
    } else if (dj <= -191) {
#pragma unroll
      for (int ct = 0; ct < 4; ++ct)
#pragma unroll
        for (int reg = 0; reg < 4; ++reg)
          p[ct][reg] = sacc[ct][reg] * SC + rpL;
    } else {
#pragma unroll
      for (int ct = 0; ct < 4; ++ct) {
#pragma unroll
        for (int reg = 0; reg < 4; ++reg) {
          int j = j0 + ct * 16 + q4 * 4 + reg;
          int off = j - ig;
          off = (off < -128) ? -128 : (off > 128 ? 128 : off);
          p[ct][reg] = sacc[ct][reg] * SC + bf2f(rpbase[off + 128]);
        }
      }
    }

    // online softmax: in-lane tree + xor16/xor32 (quads hold disjoint j's)
    float mm;
    {
      float a0 = fmaxf(fmaxf(p[0][0], p[0][1]), fmaxf(p[0][2], p[0][3]));
      float a1 = fmaxf(fmaxf(p[1][0], p[1][1]), fmaxf(p[1][2], p[1][3]));
      float a2 = fmaxf(fmaxf(p[2][0], p[2][1]), fmaxf(p[2][2], p[2][3]));
      float a3 = fmaxf(fmaxf(p[3][0], p[3][1]), fmaxf(p[3][2], p[3][3]));
      mm = fmaxf(fmaxf(a0, a1), fmaxf(a2, a3));
      mm = fmaxf(mm, __shfl_xor(mm, 16));
      mm = fmaxf(mm, __shfl_xor(mm, 32));
    }
    const float mnew = fmaxf(m_s, mm);
    const float alpha = fexp2(m_s - mnew);
    m_s = mnew;
#pragma unroll
    for (int ct = 0; ct < 4; ++ct)
#pragma unroll
      for (int reg = 0; reg < 4; ++reg)
        p[ct][reg] = fexp2(p[ct][reg] - m_s);
    {
      float s0 = (p[0][0] + p[0][1]) + (p[0][2] + p[0][3]);
      float s1 = (p[1][0] + p[1][1]) + (p[1][2] + p[1][3]);
      float s2 = (p[2][0] + p[2][1]) + (p[2][2] + p[2][3]);
      float s3 = (p[3][0] + p[3][1]) + (p[3][2] + p[3][3]);
      float rs = (s0 + s1) + (s2 + s3);
      rs += __shfl_xor(rs, 16);
      rs += __shfl_xor(rs, 32);
      l_s = l_s * alpha + rs;
    }
#pragma unroll
    for (int ct = 0; ct < 4; ++ct)
#pragma unroll
      for (int reg = 0; reg < 4; ++reg)
        oacc[ct][reg] *= alpha;

    // P^T (C-layout) -> Ps[i][j] as packed b32, chunk-swizzled (2-way free).
    unsigned int* Pw = (unsigned int*)Ps;
#pragma unroll
    for (int ct = 0; ct < 4; ++ct) {
      unsigned int pk01 = pkbf(p[ct][0], p[ct][1]);
      unsigned int pk23 = pkbf(p[ct][2], p[ct][3]);
      int chunk = ct * 2 + (q4 >> 1);
      unsigned int a = rloc * 32 + ((chunk ^ sw) << 2) + ((q4 & 1) << 1);
      Pw[a] = pk01;
      Pw[a + 1] = pk23;
    }

    // PV: out^T += V^T P^T ; pf = B-frag rows = Q rows (read own row)
    bfrag pf0 = *(const bfrag*)(Ps + rloc * 64 + (q4 ^ sw) * 8);
    bfrag pf1 = *(const bfrag*)(Ps + rloc * 64 + ((4 + q4) ^ sw) * 8);
#pragma unroll
    for (int ct = 0; ct < 4; ++ct) {
      bfrag v0f = *(const bfrag*)(Vs + (ct * 16 + l16) * 64 + (q4 ^ sw) * 8);
      bfrag v1f = *(const bfrag*)(Vs + (ct * 16 + l16) * 64 + ((4 + q4) ^ sw) * 8);
      oacc[ct] = MFMA16(v0f, pf0, oacc[ct]);
      oacc[ct] = MFMA16(v1f, pf1, oacc[ct]);
    }
    __syncthreads();
  }

  const int bidx = bh >> 4, hh = bh & 15;
  const float inv = 1.0f / l_s;
  float* orow = out + ((size_t)bidx * SEQ + ig) * DMOD + hh * HDIM;
#pragma unroll
  for (int ct = 0; ct < 4; ++ct) {
    float4 v;
    v.x = oacc[ct][0] * inv;
    v.y = oacc[ct][1] * inv;
    v.z = oacc[ct][2] * inv;
    v.w = oacc[ct][3] * inv;
    *(float4*)(orow + ct * 16 + q4 * 4) = v;
  }
}

// ------------------- launch -------------------
extern "C" void kernel_launch(void* const* d_in, const int* in_sizes, int n_in,
                              void* d_out, int out_size, void* d_ws, size_t ws_size,
                              hipStream_t stream) {
  const float* x    = (const float*)d_in[0];  // [2,2048,1024]
  const float* Wqkv = (const float*)d_in[1];  // [3072,1024]
  const float* bqkv = (const float*)d_in[2];  // [3072]
  const float* Wr   = (const float*)d_in[3];  // [257,64]
  const float* br   = (const float*)d_in[4];  // [257]
  float* out = (float*)d_out;                 // [2,2048,1024] fp32

  char* ws = (char*)d_ws;
  unsigned short* xb   = (unsigned short*)(ws);               // 8 MB
  unsigned short* wb   = (unsigned short*)(ws + 8388608);     // 6 MB
  unsigned short* qb   = (unsigned short*)(ws + 14680064);    // 8 MB
  unsigned short* kb   = (unsigned short*)(ws + 23068672);    // 8 MB
  unsigned short* vtb  = (unsigned short*)(ws + 31457280);    // 8 MB (transposed V)
  unsigned short* wrb  = (unsigned short*)(ws + 39845888);    // 34816 B
  unsigned short* rp16 = (unsigned short*)(ws + 39880704);    // 34.1 MB (bf16, ×log2e, stride 260)

  cast_all<<<7185, 256, 0, stream>>>(x, Wqkv, Wr, xb, wb, wrb);
  qkv_gemm<<<dim3(24, 32), 256, 0, stream>>>(xb, wb, bqkv, qb, kb, vtb);
  rp_gemm<<<1024, 256, 0, stream>>>(qb, wrb, br, rp16);
  flash_attn<<<dim3(32, 32), 256, 0, stream>>>(qb, kb, vtb, rp16, out);
}